// Round 6
// baseline (212.458 us; speedup 1.0000x reference)
//
#include <hip/hip_runtime.h>

// YOLO loss: input [B,30,7,7] f32, target [B,7,7,30] f32 -> scalar f32.
//
// Round 6: five structurally different kernels all pinned at 71-80 us =
// 2.65 TB/s demand -> testing the "fabric read-direction ceiling ~3.1 TB/s"
// model by maximally mimicking the copy ubench: wave-local streaming.
// Each wave owns 64 cells = 7680 B of target, loaded as 7.5 coalesced
// float4/lane (only ~30 live VGPRs -> no pressure-driven serialization),
// staged into a WAVE-PRIVATE LDS region (no __syncthreads; same-wave
// lgkmcnt ordering), read back at stride-30 (2-way bank alias = free).
// Input read directly per-lane (naturally coalesced), low-pressure phases.

#define NCH    30
#define CELLS  49
#define TPB    256
#define WPB    4                 // waves per block
#define WF4    480               // float4 per wave tile (64 cells * 120B / 16)
#define IMGSZ  448.0f
#define CELLSZ 64.0f

__device__ __forceinline__ float iou_f(float ax1, float ay1, float ax2, float ay2,
                                       float bx1, float by1, float bx2, float by2) {
    float l  = fmaxf(ax1, bx1);
    float r  = fminf(ax2, bx2);
    float t  = fmaxf(ay1, by1);
    float bo = fminf(ay2, by2);
    bool  m  = (l < r) && (t < bo);
    float inter = (r - l) * (bo - t);
    float uni   = (ax2 - ax1) * (ay2 - ay1) + (bx2 - bx1) * (by2 - by1);
    float denom = uni - inter;
    return m ? (inter / denom) : 0.0f;
}

__device__ __forceinline__ void decode_box(float p0, float p1, float p2, float p3,
                                           float gx, float gy,
                                           float& x1, float& y1, float& x2, float& y2) {
    float cx = p0 * CELLSZ + gx;
    float cy = p1 * CELLSZ + gy;
    float w  = p2 * IMGSZ;
    float h  = p3 * IMGSZ;
    x1 = fminf(fmaxf(cx - w * 0.5f, 0.0f), IMGSZ);
    y1 = fminf(fmaxf(cy - h * 0.5f, 0.0f), IMGSZ);
    x2 = fminf(fmaxf(cx + w * 0.5f, 0.0f), IMGSZ);
    y2 = fminf(fmaxf(cy + h * 0.5f, 0.0f), IMGSZ);
}

__global__ __launch_bounds__(TPB) void yolo_loss_kernel(
        const float* __restrict__ input,   // [B,30,7,7]
        const float* __restrict__ target,  // [B,7,7,30]
        float* __restrict__ out,
        int ncells) {
    __shared__ __align__(16) float stg[WPB * WF4 * 4];   // 30720 B, wave-private slices
    __shared__ float red[WPB];

    const int tid  = threadIdx.x;
    const int wid  = tid >> 6;
    const int lane = tid & 63;
    const long long gw = (long long)blockIdx.x * WPB + wid;   // global wave id
    const long long n0 = gw * 64;                              // wave's first cell

    // ---- wave-local target staging: coalesced float4, no barrier ----
    const float4* __restrict__ tp4 = reinterpret_cast<const float4*>(target) + gw * WF4;
    float4* s4 = reinterpret_cast<float4*>(&stg[wid * WF4 * 4]);
    const long long tot_f4 = (long long)ncells * NCH / 4;      // global float4 count
    const long long base4  = gw * WF4;
    #pragma unroll
    for (int k = 0; k < 7; ++k) {                              // 7 full rounds (448)
        int i = lane + 64 * k;
        if (base4 + i < tot_f4) s4[i] = tp4[i];
    }
    {                                                          // half round (480 total)
        int i = 448 + lane;
        if (lane < 32 && base4 + i < tot_f4) s4[i] = tp4[i];
    }
    // compiler inserts s_waitcnt lgkmcnt before dependent ds_read (same wave,
    // wave-private region -> no __syncthreads needed)

    const long long n = n0 + lane;
    float loss = 0.0f;
    if (n < ncells) {
        const int b    = (int)(n / CELLS);
        const int cell = (int)(n - (long long)b * CELLS);
        const int row  = cell / 7;
        const int col  = cell - row * 7;
        const float gx = (float)col * CELLSZ;
        const float gy = (float)row * CELLSZ;

        const float* __restrict__ ip = input + (long long)b * (NCH * CELLS) + cell;
        const float* __restrict__ tl = &stg[wid * WF4 * 4] + lane * NCH;

        // Phase A: input box channels 0..9 (10 live regs, coalesced dwords)
        float x0 = ip[0 * CELLS], x1 = ip[1 * CELLS], x2 = ip[2 * CELLS],
              x3 = ip[3 * CELLS], x4 = ip[4 * CELLS], x5 = ip[5 * CELLS],
              x6 = ip[6 * CELLS], x7 = ip[7 * CELLS], x8 = ip[8 * CELLS],
              x9 = ip[9 * CELLS];

        float p0x1, p0y1, p0x2, p0y2, p1x1, p1y1, p1x2, p1y2;
        decode_box(x0, x1, x2, x3, gx, gy, p0x1, p0y1, p0x2, p0y2);
        decode_box(x5, x6, x7, x8, gx, gy, p1x1, p1y1, p1x2, p1y2);
        float t0x1, t0y1, t0x2, t0y2, t1x1, t1y1, t1x2, t1y2;
        decode_box(tl[0], tl[1], tl[2], tl[3], gx, gy, t0x1, t0y1, t0x2, t0y2);
        decode_box(tl[5], tl[6], tl[7], tl[8], gx, gy, t1x1, t1y1, t1x2, t1y2);

        float iou1 = iou_f(p0x1, p0y1, p0x2, p0y2, t0x1, t0y1, t0x2, t0y2);
        float iou2 = iou_f(p1x1, p1y1, p1x2, p1y2, t1x1, t1y1, t1x2, t1y2);

        bool  mask = iou1 < iou2;
        float iou  = mask ? iou2 : iou1;
        float s0 = mask ? x5 : x0;
        float s1 = mask ? x6 : x1;
        float s2 = mask ? x7 : x2;
        float s3 = mask ? x8 : x3;
        float s4v = mask ? x9 : x4;

        float w = (tl[4] == 1.0f) ? 1.0f : 0.0f;

        float d0 = s0 - tl[0];
        float d1 = s1 - tl[1];
        float coord = d0 * d0 + d1 * d1;

        float ds2 = sqrtf(s2) - sqrtf(tl[2]);
        float ds3 = sqrtf(s3) - sqrtf(tl[3]);
        float size = ds2 * ds2 + ds3 * ds3;

        float dc = s4v - iou;
        float conf = dc * dc;
        float noobj = s4v * s4v;

        // Phase B: class channels, low pressure, immediate consumption
        float cls = 0.0f;
        #pragma unroll
        for (int c = 10; c < NCH; ++c) {
            float d = ip[c * CELLS] - tl[c];
            cls += d * d;
        }

        loss = w * (5.0f * (coord + size) + conf + cls) + 0.5f * (1.0f - w) * noobj;
    }

    // Wave reduce (64 lanes), then tiny block reduce, one atomic per block.
    #pragma unroll
    for (int off = 32; off > 0; off >>= 1)
        loss += __shfl_down(loss, off, 64);

    if (lane == 0) red[wid] = loss;
    __syncthreads();
    if (tid == 0) {
        float s = 0.0f;
        #pragma unroll
        for (int i = 0; i < WPB; ++i) s += red[i];
        atomicAdd(out, s);
    }
}

extern "C" void kernel_launch(void* const* d_in, const int* in_sizes, int n_in,
                              void* d_out, int out_size, void* d_ws, size_t ws_size,
                              hipStream_t stream) {
    const float* input  = (const float*)d_in[0];   // [B,30,7,7]
    const float* target = (const float*)d_in[1];   // [B,7,7,30]
    float* out = (float*)d_out;

    const int ncells = in_sizes[0] / NCH;                    // B*49 = 802816 (= 64*12544)
    const int blocks = (ncells + TPB - 1) / TPB;             // 3136

    // d_out is poisoned 0xAA before every timed launch -> zero it (capture-safe).
    hipMemsetAsync(d_out, 0, sizeof(float), stream);
    yolo_loss_kernel<<<blocks, TPB, 0, stream>>>(input, target, out, ncells);
}